// Round 2
// baseline (417.792 us; speedup 1.0000x reference)
//
#include <hip/hip_runtime.h>
#include <cmath>

#define HH 32
#define WW 32
#define HWN 1024
#define NCH 384
#define NHH 12
#define DHH 32
#define NGG 6

static constexpr float SCALE_QK = 0.17677669529663689f; // 32^-0.5

// ---------------------------------------------------------------------------
// K1/K4: fp32 GEMM  C[2048,N] = A[2048,K] @ W[K,N] + bias, 3-way z-select
// 64x64 tile, BK=16, 256 threads, 4x4 micro tile.
// ---------------------------------------------------------------------------
__global__ __launch_bounds__(256) void gemm3_kernel(
    const float* __restrict__ A,
    const float* __restrict__ W0, const float* __restrict__ W1, const float* __restrict__ W2,
    const float* __restrict__ b0, const float* __restrict__ b1, const float* __restrict__ b2,
    float* __restrict__ C0, float* __restrict__ C1, float* __restrict__ C2,
    int N, int K)
{
    const float* Wm = (blockIdx.z == 0) ? W0 : (blockIdx.z == 1) ? W1 : W2;
    const float* bm = (blockIdx.z == 0) ? b0 : (blockIdx.z == 1) ? b1 : b2;
    float*       Cm = (blockIdx.z == 0) ? C0 : (blockIdx.z == 1) ? C1 : C2;

    const int m0 = blockIdx.x * 64;
    const int n0 = blockIdx.y * 64;
    const int tid = threadIdx.x;
    const int tm = tid >> 4;   // 0..15
    const int tn = tid & 15;   // 0..15

    __shared__ float As[16][68];
    __shared__ float Bs[16][68];

    float acc[4][4] = {};

    for (int k0 = 0; k0 < K; k0 += 16) {
#pragma unroll
        for (int r = 0; r < 4; ++r) {
            int e = tid + r * 256;
            int row = e >> 4, kk = e & 15;
            As[kk][row] = A[(m0 + row) * K + k0 + kk];
            int kk2 = e >> 6, col = e & 63;
            Bs[kk2][col] = Wm[(k0 + kk2) * N + n0 + col];
        }
        __syncthreads();
#pragma unroll
        for (int kk = 0; kk < 16; ++kk) {
            float4 a4 = *(const float4*)&As[kk][tm * 4];
            float4 b4 = *(const float4*)&Bs[kk][tn * 4];
            float av[4] = {a4.x, a4.y, a4.z, a4.w};
            float bv[4] = {b4.x, b4.y, b4.z, b4.w};
#pragma unroll
            for (int i2 = 0; i2 < 4; ++i2)
#pragma unroll
                for (int j2 = 0; j2 < 4; ++j2)
                    acc[i2][j2] += av[i2] * bv[j2];
        }
        __syncthreads();
    }

#pragma unroll
    for (int i2 = 0; i2 < 4; ++i2) {
        float4 o4;
        o4.x = acc[i2][0] + bm[n0 + tn * 4 + 0];
        o4.y = acc[i2][1] + bm[n0 + tn * 4 + 1];
        o4.z = acc[i2][2] + bm[n0 + tn * 4 + 2];
        o4.w = acc[i2][3] + bm[n0 + tn * 4 + 3];
        *(float4*)&Cm[(m0 + tm * 4 + i2) * N + n0 + tn * 4] = o4;
    }
}

// ---------------------------------------------------------------------------
// K2: grouped 3x3 conv (SAME) -> LN -> GELU -> offset proj -> pos/ref
// ---------------------------------------------------------------------------
__global__ __launch_bounds__(384) void conv_offset_kernel(
    const float* __restrict__ q, const float* __restrict__ w_off,
    const float* __restrict__ b_off, const float* __restrict__ ln_g,
    const float* __restrict__ ln_b, const float* __restrict__ w_offp,
    float* __restrict__ pos_ws, float* __restrict__ pos_out,
    float* __restrict__ ref_out)
{
    const int b  = blockIdx.z;
    const int i  = blockIdx.y;
    const int j0 = blockIdx.x * 8;
    const int tid = threadIdx.x;
    const int g   = tid >> 6;
    const int lane = tid & 63;

    __shared__ float qs[3][10][NCH];
    __shared__ float red[6][8][2];

    for (int idx = tid; idx < 3 * 10 * NCH; idx += 384) {
        int r = idx / (10 * NCH);
        int rem = idx - r * (10 * NCH);
        int col = rem / NCH;
        int c = rem - col * NCH;
        int ii = i + r - 1;
        int jj = j0 + col - 1;
        float vv = 0.f;
        if (ii >= 0 && ii < HH && jj >= 0 && jj < WW)
            vv = q[((b * HH + ii) * WW + jj) * NCH + c];
        qs[r][col][c] = vv;
    }
    __syncthreads();

    const float bo0 = b_off[tid];
    float acc[8];
#pragma unroll
    for (int p = 0; p < 8; ++p) acc[p] = bo0;

    for (int r = 0; r < 3; ++r) {
        for (int c4 = 0; c4 < 16; ++c4) {
            float wgt[3][4];
#pragma unroll
            for (int kw = 0; kw < 3; ++kw)
#pragma unroll
                for (int u = 0; u < 4; ++u)
                    wgt[kw][u] = w_off[(((r * 3 + kw) * 64) + c4 * 4 + u) * NCH + tid];
#pragma unroll
            for (int col = 0; col < 10; ++col) {
                float4 qv = *(const float4*)&qs[r][col][(g << 6) + c4 * 4];
#pragma unroll
                for (int kw = 0; kw < 3; ++kw) {
                    int p = col - kw;
                    if (p >= 0 && p < 8)
                        acc[p] += wgt[kw][0] * qv.x + wgt[kw][1] * qv.y
                                + wgt[kw][2] * qv.z + wgt[kw][3] * qv.w;
                }
            }
        }
    }

#pragma unroll
    for (int p = 0; p < 8; ++p) {
        float v = acc[p];
        float s1 = v, s2 = v * v;
#pragma unroll
        for (int off = 32; off > 0; off >>= 1) {
            s1 += __shfl_xor(s1, off);
            s2 += __shfl_xor(s2, off);
        }
        if (lane == 0) { red[g][p][0] = s1; red[g][p][1] = s2; }
    }
    __syncthreads();

    const float gain = ln_g[tid];
    const float beta = ln_b[tid];
    const float wp0 = w_offp[lane * 2 + 0];
    const float wp1 = w_offp[lane * 2 + 1];

#pragma unroll
    for (int p = 0; p < 8; ++p) {
        float s1 = 0.f, s2 = 0.f;
#pragma unroll
        for (int w2 = 0; w2 < 6; ++w2) { s1 += red[w2][p][0]; s2 += red[w2][p][1]; }
        float mu  = s1 * (1.f / 384.f);
        float var = s2 * (1.f / 384.f) - mu * mu;
        float rs2 = rsqrtf(var + 1e-3f);
        float on = (acc[p] - mu) * rs2 * gain + beta;
        float t = 0.7978845608028654f * (on + 0.044715f * on * on * on);
        float ge = on * 0.5f * (1.f + tanhf(t));

        float t0 = ge * wp0, t1 = ge * wp1;
#pragma unroll
        for (int off = 32; off > 0; off >>= 1) {
            t0 += __shfl_xor(t0, off);
            t1 += __shfl_xor(t1, off);
        }
        if (lane == 0) {
            int jj = j0 + p;
            float o0 = tanhf(t0) * 16.f + (float)jj;
            float o1 = tanhf(t1) * 16.f + (float)i;
            int base = (((b * NGG + g) * HWN) + i * WW + jj) * 2;
            pos_ws[base]      = o0; pos_ws[base + 1]  = o1;
            pos_out[base]     = o0; pos_out[base + 1] = o1;
            ref_out[base]     = (float)jj; ref_out[base + 1] = (float)i;
        }
    }
}

// ---------------------------------------------------------------------------
// K3: fused attention, ILP-restructured.
// Block = 32 queries x 8 key-chunks of 128 (256 threads; ksub = tid>>5).
// Keys processed in chunks of 8: independent dots + bias, one chunk-max,
// deferred rescale, 8 exps, 8 V sweeps. Bilinear weights hoisted per-key
// (query coords are integers -> fractional parts are key-only).
// Grid 768 blocks = exactly 3 blocks/CU, 12 waves/CU.
// ---------------------------------------------------------------------------
__global__ __launch_bounds__(256) void attn_kernel(
    const float* __restrict__ q_ws, const float* __restrict__ k_ws,
    const float* __restrict__ v_ws, const float* __restrict__ pos_ws,
    const float* __restrict__ rpe, float* __restrict__ o_ws)
{
    const int bh = blockIdx.y;
    const int b = bh / NHH;
    const int h = bh - b * NHH;
    const int g = h >> 1;
    const int tid = threadIdx.x;
    const int ksub = tid >> 5;        // 0..7, key chunk of 128
    const int qloc = tid & 31;
    const int qn = blockIdx.x * 32 + qloc;

    __shared__ float rs[63 * 63];
    __shared__ float accs[8][DHH][32];
    __shared__ float mls[8][2][32];

    for (int idx = tid; idx < 63 * 63; idx += 256)
        rs[idx] = rpe[idx * NHH + h];

    float ql[DHH];
    {
        const float* qp = q_ws + ((b * HWN) + qn) * NCH + h * DHH;
#pragma unroll
        for (int d4 = 0; d4 < 8; ++d4) {
            float4 t = *(const float4*)(qp + d4 * 4);
            ql[d4 * 4 + 0] = t.x * SCALE_QK;
            ql[d4 * 4 + 1] = t.y * SCALE_QK;
            ql[d4 * 4 + 2] = t.z * SCALE_QK;
            ql[d4 * 4 + 3] = t.w * SCALE_QK;
        }
    }
    const int qi = qn >> 5;       // row i of query
    const int qj = qn & 31;       // col j of query

    float m = -1e30f, l = 0.f;
    float acc[DHH];
#pragma unroll
    for (int d = 0; d < DHH; ++d) acc[d] = 0.f;

    __syncthreads();

    const float* kb = k_ws + (b * HWN) * NCH + h * DHH;
    const float* vb = v_ws + (b * HWN) * NCH + h * DHH;
    const float* pb = pos_ws + (b * NGG + g) * (HWN * 2);

    const int sbase = ksub * 128;
    for (int c = 0; c < 128; c += 8) {
        float sc[8];
        // --- 8 independent dot products ---
#pragma unroll
        for (int t = 0; t < 8; ++t) {
            const float* kr = kb + (sbase + c + t) * NCH;
            float d0 = 0.f, d1 = 0.f, d2 = 0.f, d3 = 0.f;
#pragma unroll
            for (int d4 = 0; d4 < 8; ++d4) {
                float4 kv = *(const float4*)(kr + d4 * 4);
                d0 += kv.x * ql[d4 * 4 + 0];
                d1 += kv.y * ql[d4 * 4 + 1];
                d2 += kv.z * ql[d4 * 4 + 2];
                d3 += kv.w * ql[d4 * 4 + 3];
            }
            sc[t] = (d0 + d1) + (d2 + d3);
        }
        // --- 8 independent bias samples (weights hoisted per key) ---
#pragma unroll
        for (int t = 0; t < 8; ++t) {
            int s = sbase + c + t;
            float p0 = pb[s * 2 + 0];
            float p1 = pb[s * 2 + 1];
            float mp1 = -p1, mp0 = -p0;
            float fxf = floorf(mp1), fyf = floorf(mp0);
            float wx = mp1 - fxf, wy = mp0 - fyf;
            float w00 = (1.f - wx) * (1.f - wy);
            float w01 = wx * (1.f - wy);
            float w10 = (1.f - wx) * wy;
            float w11 = wx * wy;
            int ix = qi + (int)fxf;
            int iy = qj + (int)fyf;
            int cx0 = min(max(ix, 0), 62);
            int cx1 = min(max(ix + 1, 0), 62);
            int cy0 = min(max(iy, 0), 62);
            int cy1 = min(max(iy + 1, 0), 62);
            bool mx0 = (unsigned)ix < 63u;
            bool mx1 = (unsigned)(ix + 1) < 63u;
            bool my0 = (unsigned)iy < 63u;
            bool my1 = (unsigned)(iy + 1) < 63u;
            int r0 = cy0 * 63, r1 = cy1 * 63;
            float v00 = (mx0 && my0) ? rs[r0 + cx0] : 0.f;
            float v01 = (mx1 && my0) ? rs[r0 + cx1] : 0.f;
            float v10 = (mx0 && my1) ? rs[r1 + cx0] : 0.f;
            float v11 = (mx1 && my1) ? rs[r1 + cx1] : 0.f;
            sc[t] += v00 * w00 + v01 * w01 + v10 * w10 + v11 * w11;
        }
        // --- chunk max + deferred rescale ---
        float cmax = fmaxf(fmaxf(fmaxf(sc[0], sc[1]), fmaxf(sc[2], sc[3])),
                           fmaxf(fmaxf(sc[4], sc[5]), fmaxf(sc[6], sc[7])));
        if (cmax > m + 8.f) {
            float scl = __expf(m - cmax);
            m = cmax;
            l *= scl;
#pragma unroll
            for (int d = 0; d < DHH; ++d) acc[d] *= scl;
        }
        float pr[8];
#pragma unroll
        for (int t = 0; t < 8; ++t) {
            pr[t] = __expf(sc[t] - m);
            l += pr[t];
        }
        // --- 8 V-row accumulations ---
#pragma unroll
        for (int t = 0; t < 8; ++t) {
            const float* vr = vb + (sbase + c + t) * NCH;
#pragma unroll
            for (int d4 = 0; d4 < 8; ++d4) {
                float4 vv = *(const float4*)(vr + d4 * 4);
                acc[d4 * 4 + 0] += pr[t] * vv.x;
                acc[d4 * 4 + 1] += pr[t] * vv.y;
                acc[d4 * 4 + 2] += pr[t] * vv.z;
                acc[d4 * 4 + 3] += pr[t] * vv.w;
            }
        }
    }

    mls[ksub][0][qloc] = m;
    mls[ksub][1][qloc] = l;
#pragma unroll
    for (int d = 0; d < DHH; ++d) accs[ksub][d][qloc] = acc[d];
    __syncthreads();

    // --- combine 8 chunk-partials: thread = (query, d-quad) ---
    const int q2 = tid & 31;
    const int dg = tid >> 5;           // 0..7 -> d = dg*4..dg*4+3
    const int qn2 = blockIdx.x * 32 + q2;
    float mstar = -1e30f;
#pragma unroll
    for (int w2 = 0; w2 < 8; ++w2) mstar = fmaxf(mstar, mls[w2][0][q2]);
    float wgt[8];
    float lsum = 0.f;
#pragma unroll
    for (int w2 = 0; w2 < 8; ++w2) {
        wgt[w2] = __expf(mls[w2][0][q2] - mstar);
        lsum += wgt[w2] * mls[w2][1][q2];
    }
    float inv = 1.f / lsum;
    float4 o4;
    float ov[4];
#pragma unroll
    for (int u = 0; u < 4; ++u) {
        float o = 0.f;
#pragma unroll
        for (int w2 = 0; w2 < 8; ++w2)
            o += wgt[w2] * accs[w2][dg * 4 + u][q2];
        ov[u] = o * inv;
    }
    o4.x = ov[0]; o4.y = ov[1]; o4.z = ov[2]; o4.w = ov[3];
    *(float4*)&o_ws[((b * HWN) + qn2) * NCH + h * DHH + dg * 4] = o4;
}

// ---------------------------------------------------------------------------
extern "C" void kernel_launch(void* const* d_in, const int* in_sizes, int n_in,
                              void* d_out, int out_size, void* d_ws, size_t ws_size,
                              hipStream_t stream) {
    (void)in_sizes; (void)n_in; (void)out_size; (void)ws_size;
    const float* x      = (const float*)d_in[0];
    const float* w_off  = (const float*)d_in[1];
    const float* b_off  = (const float*)d_in[2];
    const float* ln_g   = (const float*)d_in[3];
    const float* ln_b   = (const float*)d_in[4];
    const float* w_offp = (const float*)d_in[5];
    const float* wq     = (const float*)d_in[6];
    const float* bq     = (const float*)d_in[7];
    const float* wk     = (const float*)d_in[8];
    const float* bk     = (const float*)d_in[9];
    const float* wv     = (const float*)d_in[10];
    const float* bv     = (const float*)d_in[11];
    const float* wo     = (const float*)d_in[12];
    const float* bo     = (const float*)d_in[13];
    const float* rpe    = (const float*)d_in[14];

    float* out     = (float*)d_out;
    float* y_out   = out;             // 786432
    float* pos_out = out + 786432;    // 24576
    float* ref_out = out + 811008;    // 24576

    float* ws     = (float*)d_ws;
    float* q_ws   = ws;               // 786432
    float* k_ws   = ws + 786432;      // 786432
    float* v_ws   = ws + 1572864;     // 786432
    float* o_ws   = ws + 2359296;     // 786432
    float* pos_ws = ws + 3145728;     // 24576

    gemm3_kernel<<<dim3(32, 6, 3), 256, 0, stream>>>(
        x, wq, wk, wv, bq, bk, bv, q_ws, k_ws, v_ws, NCH, NCH);

    conv_offset_kernel<<<dim3(4, 32, 2), 384, 0, stream>>>(
        q_ws, w_off, b_off, ln_g, ln_b, w_offp, pos_ws, pos_out, ref_out);

    attn_kernel<<<dim3(32, 24), 256, 0, stream>>>(
        q_ws, k_ws, v_ws, pos_ws, rpe, o_ws);

    gemm3_kernel<<<dim3(32, 6, 1), 256, 0, stream>>>(
        o_ws, wo, wo, wo, bo, bo, bo, y_out, y_out, y_out, NCH, NCH);
}

// Round 3
// 174.717 us; speedup vs baseline: 2.3912x; 2.3912x over previous
//
#include <hip/hip_runtime.h>
#include <cmath>

#define HH 32
#define WW 32
#define HWN 1024
#define NCH 384
#define NHH 12
#define DHH 32
#define NGG 6

typedef __attribute__((ext_vector_type(8))) short short8;
typedef __attribute__((ext_vector_type(4))) float f32x4;

static constexpr float SCALE_QK = 0.17677669529663689f;     // 32^-0.5
static constexpr float INV_SCALE_QK = 5.656854249492381f;   // 32^0.5

__device__ inline unsigned short f2bf(float f) {
    union { float f; unsigned u; } v; v.f = f;
    return (unsigned short)((v.u + 0x7FFFu + ((v.u >> 16) & 1u)) >> 16);  // RNE
}
__device__ inline float bf2f(unsigned short s) {
    union { unsigned u; float f; } v; v.u = ((unsigned)s) << 16;
    return v.f;
}

// ---------------------------------------------------------------------------
// MFMA GEMM: C[2048,384] = bf16(A[2048,384]) @ bf16(W) + bias.
// 64x64 tile, 4 waves of 32x32 (2x2 16x16 frags), K-step 32, fragments loaded
// directly from global (all operands L2-resident), fp32 accumulate.
// kmode=0: fp32 store to Cf (z=0 only). kmode=1: z=0 -> Qb bf16 (*SCALE_QK),
// z=1 -> Kb bf16, z=2 -> Vt bf16 transposed [bh][d][k].
// ---------------------------------------------------------------------------
__global__ __launch_bounds__(256) void gemm_mfma(
    const float* __restrict__ A,
    const float* __restrict__ W0, const float* __restrict__ W1, const float* __restrict__ W2,
    const float* __restrict__ b0, const float* __restrict__ b1, const float* __restrict__ b2,
    float* __restrict__ Cf,
    unsigned short* __restrict__ Qb, unsigned short* __restrict__ Kb,
    unsigned short* __restrict__ Vt, int kmode)
{
    const int z = blockIdx.z;
    const float* Wm = (z == 0) ? W0 : (z == 1) ? W1 : W2;
    const float* bm = (z == 0) ? b0 : (z == 1) ? b1 : b2;
    const int lane = threadIdx.x & 63;
    const int wid  = threadIdx.x >> 6;
    const int g    = lane >> 4;
    const int l15  = lane & 15;
    const int m0w  = blockIdx.x * 64 + (wid >> 1) * 32;
    const int n0w  = blockIdx.y * 64 + (wid & 1) * 32;

    f32x4 acc[2][2] = {};

#pragma unroll 2
    for (int k0 = 0; k0 < NCH; k0 += 32) {
        short8 af[2];
#pragma unroll
        for (int i = 0; i < 2; ++i) {
            const float* ap = A + (m0w + i * 16 + l15) * NCH + k0 + g * 8;
            float4 a0 = *(const float4*)ap;
            float4 a1 = *(const float4*)(ap + 4);
            short8 t;
            t[0] = (short)f2bf(a0.x); t[1] = (short)f2bf(a0.y);
            t[2] = (short)f2bf(a0.z); t[3] = (short)f2bf(a0.w);
            t[4] = (short)f2bf(a1.x); t[5] = (short)f2bf(a1.y);
            t[6] = (short)f2bf(a1.z); t[7] = (short)f2bf(a1.w);
            af[i] = t;
        }
        short8 bfr[2];
#pragma unroll
        for (int j = 0; j < 2; ++j) {
            const float* wp = Wm + (k0 + g * 8) * NCH + n0w + j * 16 + l15;
            short8 t;
#pragma unroll
            for (int u = 0; u < 8; ++u) t[u] = (short)f2bf(wp[u * NCH]);
            bfr[j] = t;
        }
#pragma unroll
        for (int i = 0; i < 2; ++i)
#pragma unroll
            for (int j = 0; j < 2; ++j)
                acc[i][j] = __builtin_amdgcn_mfma_f32_16x16x32_bf16(
                    af[i], bfr[j], acc[i][j], 0, 0, 0);
    }

    if (kmode == 0) {
#pragma unroll
        for (int i = 0; i < 2; ++i)
#pragma unroll
            for (int j = 0; j < 2; ++j) {
                int col = n0w + j * 16 + l15;
                float bias = bm[col];
#pragma unroll
                for (int r = 0; r < 4; ++r) {
                    int row = m0w + i * 16 + g * 4 + r;
                    Cf[row * NCH + col] = acc[i][j][r] + bias;
                }
            }
    } else if (z == 2) {
        // Vt[bh][d][k] bf16; 4 consecutive k per lane -> one uint2 store
#pragma unroll
        for (int i = 0; i < 2; ++i) {
            int krow = m0w + i * 16 + g * 4;
            int b_ = krow >> 10, kk = krow & 1023;
#pragma unroll
            for (int j = 0; j < 2; ++j) {
                int col = n0w + j * 16 + l15;
                int h = col >> 5, d = col & 31;
                float bias = bm[col];
                unsigned short s0 = f2bf(acc[i][j][0] + bias);
                unsigned short s1 = f2bf(acc[i][j][1] + bias);
                unsigned short s2 = f2bf(acc[i][j][2] + bias);
                unsigned short s3 = f2bf(acc[i][j][3] + bias);
                uint2 pk;
                pk.x = (unsigned)s0 | ((unsigned)s1 << 16);
                pk.y = (unsigned)s2 | ((unsigned)s3 << 16);
                *(uint2*)&Vt[(((b_ * NHH) + h) * DHH + d) * HWN + kk] = pk;
            }
        }
    } else {
        unsigned short* O = (z == 0) ? Qb : Kb;
        float scl = (z == 0) ? SCALE_QK : 1.0f;
#pragma unroll
        for (int i = 0; i < 2; ++i)
#pragma unroll
            for (int j = 0; j < 2; ++j) {
                int col = n0w + j * 16 + l15;
                int h = col >> 5, d = col & 31;
                float bias = bm[col];
#pragma unroll
                for (int r = 0; r < 4; ++r) {
                    int row = m0w + i * 16 + g * 4 + r;
                    int b_ = row >> 10, q = row & 1023;
                    O[(((b_ * NHH) + h) * HWN + q) * DHH + d] =
                        f2bf((acc[i][j][r] + bias) * scl);
                }
            }
    }
}

// ---------------------------------------------------------------------------
// K2: grouped 3x3 conv (SAME) on q -> LN -> GELU -> offset proj -> pos/ref.
// Reads q from bf16 Qb (pre-scaled by SCALE_QK; unscale on load).
// ---------------------------------------------------------------------------
__global__ __launch_bounds__(384) void conv_offset_kernel(
    const unsigned short* __restrict__ Qb, const float* __restrict__ w_off,
    const float* __restrict__ b_off, const float* __restrict__ ln_g,
    const float* __restrict__ ln_b, const float* __restrict__ w_offp,
    float* __restrict__ pos_ws, float* __restrict__ pos_out,
    float* __restrict__ ref_out)
{
    const int b  = blockIdx.z;
    const int i  = blockIdx.y;
    const int j0 = blockIdx.x * 8;
    const int tid = threadIdx.x;
    const int g   = tid >> 6;
    const int lane = tid & 63;

    __shared__ float qs[3][10][NCH];
    __shared__ float red[6][8][2];

    for (int idx = tid; idx < 3 * 10 * NCH; idx += 384) {
        int r = idx / (10 * NCH);
        int rem = idx - r * (10 * NCH);
        int col = rem / NCH;
        int c = rem - col * NCH;
        int ii = i + r - 1;
        int jj = j0 + col - 1;
        float vv = 0.f;
        if (ii >= 0 && ii < HH && jj >= 0 && jj < WW)
            vv = bf2f(Qb[(((b * NHH) + (c >> 5)) * HWN + ii * WW + jj) * DHH + (c & 31)])
                 * INV_SCALE_QK;
        qs[r][col][c] = vv;
    }
    __syncthreads();

    const float bo0 = b_off[tid];
    float acc[8];
#pragma unroll
    for (int p = 0; p < 8; ++p) acc[p] = bo0;

    for (int r = 0; r < 3; ++r) {
        for (int c4 = 0; c4 < 16; ++c4) {
            float wgt[3][4];
#pragma unroll
            for (int kw = 0; kw < 3; ++kw)
#pragma unroll
                for (int u = 0; u < 4; ++u)
                    wgt[kw][u] = w_off[(((r * 3 + kw) * 64) + c4 * 4 + u) * NCH + tid];
#pragma unroll
            for (int col = 0; col < 10; ++col) {
                float4 qv = *(const float4*)&qs[r][col][(g << 6) + c4 * 4];
#pragma unroll
                for (int kw = 0; kw < 3; ++kw) {
                    int p = col - kw;
                    if (p >= 0 && p < 8)
                        acc[p] += wgt[kw][0] * qv.x + wgt[kw][1] * qv.y
                                + wgt[kw][2] * qv.z + wgt[kw][3] * qv.w;
                }
            }
        }
    }

#pragma unroll
    for (int p = 0; p < 8; ++p) {
        float v = acc[p];
        float s1 = v, s2 = v * v;
#pragma unroll
        for (int off = 32; off > 0; off >>= 1) {
            s1 += __shfl_xor(s1, off);
            s2 += __shfl_xor(s2, off);
        }
        if (lane == 0) { red[g][p][0] = s1; red[g][p][1] = s2; }
    }
    __syncthreads();

    const float gain = ln_g[tid];
    const float beta = ln_b[tid];
    const float wp0 = w_offp[lane * 2 + 0];
    const float wp1 = w_offp[lane * 2 + 1];

#pragma unroll
    for (int p = 0; p < 8; ++p) {
        float s1 = 0.f, s2 = 0.f;
#pragma unroll
        for (int w2 = 0; w2 < 6; ++w2) { s1 += red[w2][p][0]; s2 += red[w2][p][1]; }
        float mu  = s1 * (1.f / 384.f);
        float var = s2 * (1.f / 384.f) - mu * mu;
        float rs2 = rsqrtf(var + 1e-3f);
        float on = (acc[p] - mu) * rs2 * gain + beta;
        float t = 0.7978845608028654f * (on + 0.044715f * on * on * on);
        float ge = on * 0.5f * (1.f + tanhf(t));

        float t0 = ge * wp0, t1 = ge * wp1;
#pragma unroll
        for (int off = 32; off > 0; off >>= 1) {
            t0 += __shfl_xor(t0, off);
            t1 += __shfl_xor(t1, off);
        }
        if (lane == 0) {
            int jj = j0 + p;
            float o0 = tanhf(t0) * 16.f + (float)jj;
            float o1 = tanhf(t1) * 16.f + (float)i;
            int base = (((b * NGG + g) * HWN) + i * WW + jj) * 2;
            pos_ws[base]      = o0; pos_ws[base + 1]  = o1;
            pos_out[base]     = o0; pos_out[base + 1] = o1;
            ref_out[base]     = (float)jj; ref_out[base + 1] = (float)i;
        }
    }
}

// ---------------------------------------------------------------------------
// K3: MFMA flash attention. Block = 2 waves, each wave owns 16 queries.
// Swapped QK^T: st = mfma(Kfrag, Qfrag) -> lane holds S^T[k=4g+r][q=l15].
// Bias (verified R0 formula) added per lane; cross-group max via shfl_xor;
// deferred-max online softmax; P -> bf16 -> per-wave padded LDS -> B-frag
// for PV mfma(Vt, P) accumulating O^T[d][q]. Grid 768 = 3 blocks/CU.
// ---------------------------------------------------------------------------
__global__ __launch_bounds__(128) void attn_mfma(
    const unsigned short* __restrict__ Qb, const unsigned short* __restrict__ Kb,
    const unsigned short* __restrict__ Vt, const float* __restrict__ pos_ws,
    const float* __restrict__ rpe, float* __restrict__ o_ws)
{
    const int bh = blockIdx.y;
    const int b = bh / NHH;
    const int h = bh - b * NHH;
    const int tid = threadIdx.x;
    const int wid = tid >> 6;
    const int lane = tid & 63;
    const int g = lane >> 4;
    const int l15 = lane & 15;
    const int q = blockIdx.x * 32 + wid * 16 + l15;

    __shared__ float rs[63 * 63];
    __shared__ unsigned short P_lds[2][16][40];   // [wave][q][k], pad 40 (2-way banks)

    for (int idx = tid; idx < 63 * 63; idx += 128)
        rs[idx] = rpe[idx * NHH + h];

    short8 qf = *(const short8*)(Qb + ((bh * HWN) + q) * DHH + g * 8);

    const float fqi = (float)(q >> 5);
    const float fqj = (float)(q & 31);

    const unsigned short* kbase = Kb + (bh * HWN) * DHH;
    const unsigned short* vbase = Vt + (bh * DHH) * HWN;
    const float* pb = pos_ws + (b * NGG + (h >> 1)) * (HWN * 2);

    f32x4 oacc[2] = {};
    float m = -1e30f, lpart = 0.f;
    const f32x4 z4 = {0.f, 0.f, 0.f, 0.f};

    __syncthreads();

#pragma unroll 1
    for (int kc0 = 0; kc0 < HWN; kc0 += 32) {
        f32x4 st[2];
#pragma unroll
        for (int t = 0; t < 2; ++t) {
            short8 kf = *(const short8*)(kbase + (kc0 + t * 16 + l15) * DHH + g * 8);
            st[t] = __builtin_amdgcn_mfma_f32_16x16x32_bf16(kf, qf, z4, 0, 0, 0);
        }
        // bias: lane's scores are keys k = kc0 + t*16 + g*4 + r, query fixed
#pragma unroll
        for (int t = 0; t < 2; ++t) {
#pragma unroll
            for (int r = 0; r < 4; ++r) {
                int k = kc0 + t * 16 + g * 4 + r;
                float2 pp = *(const float2*)(pb + k * 2);
                float xw = fqi - pp.y;
                float yw = fqj - pp.x;
                float x0f = floorf(xw), y0f = floorf(yw);
                float wx = xw - x0f, wy = yw - y0f;
                int ix = (int)x0f, iy = (int)y0f;
                int cx0 = min(max(ix, 0), 62), cx1 = min(max(ix + 1, 0), 62);
                int cy0 = min(max(iy, 0), 62), cy1 = min(max(iy + 1, 0), 62);
                bool mx0 = (unsigned)ix < 63u;
                bool mx1 = (unsigned)(ix + 1) < 63u;
                bool my0 = (unsigned)iy < 63u;
                bool my1 = (unsigned)(iy + 1) < 63u;
                int r0 = cy0 * 63, r1 = cy1 * 63;
                float v00 = (mx0 && my0) ? rs[r0 + cx0] : 0.f;
                float v01 = (mx1 && my0) ? rs[r0 + cx1] : 0.f;
                float v10 = (mx0 && my1) ? rs[r1 + cx0] : 0.f;
                float v11 = (mx1 && my1) ? rs[r1 + cx1] : 0.f;
                st[t][r] += (v00 * (1.f - wx) + v01 * wx) * (1.f - wy)
                          + (v10 * (1.f - wx) + v11 * wx) * wy;
            }
        }
        // chunk max over 32 keys for this query (4 lanes share q)
        float cm = fmaxf(fmaxf(fmaxf(st[0][0], st[0][1]), fmaxf(st[0][2], st[0][3])),
                         fmaxf(fmaxf(st[1][0], st[1][1]), fmaxf(st[1][2], st[1][3])));
        cm = fmaxf(cm, __shfl_xor(cm, 16));
        cm = fmaxf(cm, __shfl_xor(cm, 32));
        if (cm > m + 8.f) {                 // deferred rescale (uniform per q)
            float scl = __expf(m - cm);
            m = cm;
            lpart *= scl;
            oacc[0] *= scl;
            oacc[1] *= scl;
        }
#pragma unroll
        for (int t = 0; t < 2; ++t) {
            float p0 = __expf(st[t][0] - m);
            float p1 = __expf(st[t][1] - m);
            float p2 = __expf(st[t][2] - m);
            float p3 = __expf(st[t][3] - m);
            lpart += (p0 + p1) + (p2 + p3);
            uint2 pk;
            pk.x = (unsigned)f2bf(p0) | ((unsigned)f2bf(p1) << 16);
            pk.y = (unsigned)f2bf(p2) | ((unsigned)f2bf(p3) << 16);
            *(uint2*)&P_lds[wid][l15][t * 16 + g * 4] = pk;
        }
        short8 pf = *(const short8*)&P_lds[wid][l15][g * 8];
#pragma unroll
        for (int dt = 0; dt < 2; ++dt) {
            short8 vf = *(const short8*)(vbase + (dt * 16 + l15) * HWN + kc0 + g * 8);
            oacc[dt] = __builtin_amdgcn_mfma_f32_16x16x32_bf16(vf, pf, oacc[dt], 0, 0, 0);
        }
    }

    lpart += __shfl_xor(lpart, 16);
    lpart += __shfl_xor(lpart, 32);
    float inv = 1.f / lpart;
#pragma unroll
    for (int dt = 0; dt < 2; ++dt) {
        f32x4 o = oacc[dt] * inv;
        *(f32x4*)&o_ws[((b * HWN) + q) * NCH + h * DHH + dt * 16 + g * 4] = o;
    }
}

// ---------------------------------------------------------------------------
extern "C" void kernel_launch(void* const* d_in, const int* in_sizes, int n_in,
                              void* d_out, int out_size, void* d_ws, size_t ws_size,
                              hipStream_t stream) {
    (void)in_sizes; (void)n_in; (void)out_size; (void)ws_size;
    const float* x      = (const float*)d_in[0];
    const float* w_off  = (const float*)d_in[1];
    const float* b_off  = (const float*)d_in[2];
    const float* ln_g   = (const float*)d_in[3];
    const float* ln_b   = (const float*)d_in[4];
    const float* w_offp = (const float*)d_in[5];
    const float* wq     = (const float*)d_in[6];
    const float* bq     = (const float*)d_in[7];
    const float* wk     = (const float*)d_in[8];
    const float* bk     = (const float*)d_in[9];
    const float* wv     = (const float*)d_in[10];
    const float* bv     = (const float*)d_in[11];
    const float* wo     = (const float*)d_in[12];
    const float* bo     = (const float*)d_in[13];
    const float* rpe    = (const float*)d_in[14];

    float* out     = (float*)d_out;
    float* y_out   = out;             // 786432
    float* pos_out = out + 786432;    // 24576
    float* ref_out = out + 811008;    // 24576

    float* ws = (float*)d_ws;
    unsigned short* Qb = (unsigned short*)(ws);            // 786432 bf16
    unsigned short* Kb = (unsigned short*)(ws + 393216);   // 786432 bf16
    unsigned short* Vt = (unsigned short*)(ws + 786432);   // 786432 bf16
    float* o_ws   = ws + 1179648;                          // 786432 f32
    float* pos_ws = ws + 1966080;                          // 24576 f32

    // K1: q/k/v projections -> bf16 Qb (scaled), Kb, Vt (transposed)
    gemm_mfma<<<dim3(32, 6, 3), 256, 0, stream>>>(
        x, wq, wk, wv, bq, bk, bv, nullptr, Qb, Kb, Vt, 1);

    // K2: grouped conv + LN + GELU + offset -> pos (+ pos/ref outputs)
    conv_offset_kernel<<<dim3(4, 32, 2), 384, 0, stream>>>(
        Qb, w_off, b_off, ln_g, ln_b, w_offp, pos_ws, pos_out, ref_out);

    // K3: MFMA flash attention with bilinear RPE bias
    attn_mfma<<<dim3(32, 24), 128, 0, stream>>>(
        Qb, Kb, Vt, pos_ws, rpe, o_ws);

    // K4: output projection -> y (fp32 store)
    gemm_mfma<<<dim3(32, 6, 1), 256, 0, stream>>>(
        o_ws, wo, wo, wo, bo, bo, bo, y_out, nullptr, nullptr, nullptr, 0);
}

// Round 4
// 121.070 us; speedup vs baseline: 3.4508x; 1.4431x over previous
//
#include <hip/hip_runtime.h>
#include <cmath>

#define HH 32
#define WW 32
#define HWN 1024
#define NCH 384
#define NHH 12
#define DHH 32
#define NGG 6

typedef __attribute__((ext_vector_type(8))) short short8;
typedef __attribute__((ext_vector_type(4))) float f32x4;

static constexpr float SCALE_QK = 0.17677669529663689f;     // 32^-0.5
static constexpr float INV_SCALE_QK = 5.656854249492381f;   // 32^0.5

__device__ inline unsigned short f2bf(float f) {
    union { float f; unsigned u; } v; v.f = f;
    return (unsigned short)((v.u + 0x7FFFu + ((v.u >> 16) & 1u)) >> 16);  // RNE
}
__device__ inline float bf2f(unsigned short s) {
    union { unsigned u; float f; } v; v.u = ((unsigned)s) << 16;
    return v.f;
}

// ---------------------------------------------------------------------------
// K0: build zero-padded, head-major RPE table rpad[12][67][68]:
// rows/cols 0..1 and 65..66 are zero; [r+2][c+2] = rpe[(r*63+c)*12 + h].
// ---------------------------------------------------------------------------
__global__ __launch_bounds__(256) void rpe_pad_kernel(
    const float* __restrict__ rpe, float* __restrict__ rpad)
{
    int idx = blockIdx.x * 256 + threadIdx.x;
    if (idx >= 12 * 67 * 68) return;
    int h = idx / (67 * 68);
    int rem = idx - h * (67 * 68);
    int row = rem / 68, col = rem - row * 68;
    int r = row - 2, c = col - 2;
    float v = 0.f;
    if (r >= 0 && r < 63 && c >= 0 && c < 63)
        v = rpe[(r * 63 + c) * NHH + h];
    rpad[idx] = v;
}

// ---------------------------------------------------------------------------
// MFMA GEMM. kmode=1: A=f32 x, 3-way z -> Qb (bf16,*SCALE_QK) / Kb / Vt[bh][d][k].
// kmode=0: A=bf16 (o_bf), z=0, fp32 store to Cf + bias.
// ---------------------------------------------------------------------------
__global__ __launch_bounds__(256) void gemm_mfma(
    const float* __restrict__ A, const unsigned short* __restrict__ Abf,
    const float* __restrict__ W0, const float* __restrict__ W1, const float* __restrict__ W2,
    const float* __restrict__ b0, const float* __restrict__ b1, const float* __restrict__ b2,
    float* __restrict__ Cf,
    unsigned short* __restrict__ Qb, unsigned short* __restrict__ Kb,
    unsigned short* __restrict__ Vt, int kmode)
{
    const int z = blockIdx.z;
    const float* Wm = (z == 0) ? W0 : (z == 1) ? W1 : W2;
    const float* bm = (z == 0) ? b0 : (z == 1) ? b1 : b2;
    const int lane = threadIdx.x & 63;
    const int wid  = threadIdx.x >> 6;
    const int g    = lane >> 4;
    const int l15  = lane & 15;
    const int m0w  = blockIdx.x * 64 + (wid >> 1) * 32;
    const int n0w  = blockIdx.y * 64 + (wid & 1) * 32;

    f32x4 acc[2][2] = {};

#pragma unroll 2
    for (int k0 = 0; k0 < NCH; k0 += 32) {
        short8 af[2];
#pragma unroll
        for (int i = 0; i < 2; ++i) {
            if (kmode == 0) {
                af[i] = *(const short8*)(Abf + (m0w + i * 16 + l15) * NCH + k0 + g * 8);
            } else {
                const float* ap = A + (m0w + i * 16 + l15) * NCH + k0 + g * 8;
                float4 a0 = *(const float4*)ap;
                float4 a1 = *(const float4*)(ap + 4);
                short8 t;
                t[0] = (short)f2bf(a0.x); t[1] = (short)f2bf(a0.y);
                t[2] = (short)f2bf(a0.z); t[3] = (short)f2bf(a0.w);
                t[4] = (short)f2bf(a1.x); t[5] = (short)f2bf(a1.y);
                t[6] = (short)f2bf(a1.z); t[7] = (short)f2bf(a1.w);
                af[i] = t;
            }
        }
        short8 bfr[2];
#pragma unroll
        for (int j = 0; j < 2; ++j) {
            const float* wp = Wm + (k0 + g * 8) * NCH + n0w + j * 16 + l15;
            short8 t;
#pragma unroll
            for (int u = 0; u < 8; ++u) t[u] = (short)f2bf(wp[u * NCH]);
            bfr[j] = t;
        }
#pragma unroll
        for (int i = 0; i < 2; ++i)
#pragma unroll
            for (int j = 0; j < 2; ++j)
                acc[i][j] = __builtin_amdgcn_mfma_f32_16x16x32_bf16(
                    af[i], bfr[j], acc[i][j], 0, 0, 0);
    }

    if (kmode == 0) {
#pragma unroll
        for (int i = 0; i < 2; ++i)
#pragma unroll
            for (int j = 0; j < 2; ++j) {
                int col = n0w + j * 16 + l15;
                float bias = bm[col];
#pragma unroll
                for (int r = 0; r < 4; ++r) {
                    int row = m0w + i * 16 + g * 4 + r;
                    Cf[row * NCH + col] = acc[i][j][r] + bias;
                }
            }
    } else if (z == 2) {
#pragma unroll
        for (int i = 0; i < 2; ++i) {
            int krow = m0w + i * 16 + g * 4;
            int b_ = krow >> 10, kk = krow & 1023;
#pragma unroll
            for (int j = 0; j < 2; ++j) {
                int col = n0w + j * 16 + l15;
                int h = col >> 5, d = col & 31;
                float bias = bm[col];
                unsigned short s0 = f2bf(acc[i][j][0] + bias);
                unsigned short s1 = f2bf(acc[i][j][1] + bias);
                unsigned short s2 = f2bf(acc[i][j][2] + bias);
                unsigned short s3 = f2bf(acc[i][j][3] + bias);
                uint2 pk;
                pk.x = (unsigned)s0 | ((unsigned)s1 << 16);
                pk.y = (unsigned)s2 | ((unsigned)s3 << 16);
                *(uint2*)&Vt[(((b_ * NHH) + h) * DHH + d) * HWN + kk] = pk;
            }
        }
    } else {
        unsigned short* O = (z == 0) ? Qb : Kb;
        float scl = (z == 0) ? SCALE_QK : 1.0f;
#pragma unroll
        for (int i = 0; i < 2; ++i)
#pragma unroll
            for (int j = 0; j < 2; ++j) {
                int col = n0w + j * 16 + l15;
                int h = col >> 5, d = col & 31;
                float bias = bm[col];
#pragma unroll
                for (int r = 0; r < 4; ++r) {
                    int row = m0w + i * 16 + g * 4 + r;
                    int b_ = row >> 10, q = row & 1023;
                    O[(((b_ * NHH) + h) * HWN + q) * DHH + d] =
                        f2bf((acc[i][j][r] + bias) * scl);
                }
            }
    }
}

// ---------------------------------------------------------------------------
// K2: grouped 3x3 conv -> LN -> GELU -> offset proj -> pos/ref + per-key
// bilinear precompute (kw4 weights, kbase packed int16 floor bases).
// ---------------------------------------------------------------------------
__global__ __launch_bounds__(384) void conv_offset_kernel(
    const unsigned short* __restrict__ Qb, const float* __restrict__ w_off,
    const float* __restrict__ b_off, const float* __restrict__ ln_g,
    const float* __restrict__ ln_b, const float* __restrict__ w_offp,
    float* __restrict__ pos_out, float* __restrict__ ref_out,
    float4* __restrict__ kw4, int* __restrict__ kbase)
{
    const int b  = blockIdx.z;
    const int i  = blockIdx.y;
    const int j0 = blockIdx.x * 8;
    const int tid = threadIdx.x;
    const int g   = tid >> 6;
    const int lane = tid & 63;

    __shared__ float qs[3][10][NCH];
    __shared__ float red[6][8][2];

    for (int idx = tid; idx < 3 * 10 * NCH; idx += 384) {
        int r = idx / (10 * NCH);
        int rem = idx - r * (10 * NCH);
        int col = rem / NCH;
        int c = rem - col * NCH;
        int ii = i + r - 1;
        int jj = j0 + col - 1;
        float vv = 0.f;
        if (ii >= 0 && ii < HH && jj >= 0 && jj < WW)
            vv = bf2f(Qb[(((b * NHH) + (c >> 5)) * HWN + ii * WW + jj) * DHH + (c & 31)])
                 * INV_SCALE_QK;
        qs[r][col][c] = vv;
    }
    __syncthreads();

    const float bo0 = b_off[tid];
    float acc[8];
#pragma unroll
    for (int p = 0; p < 8; ++p) acc[p] = bo0;

    for (int r = 0; r < 3; ++r) {
        for (int c4 = 0; c4 < 16; ++c4) {
            float wgt[3][4];
#pragma unroll
            for (int kw = 0; kw < 3; ++kw)
#pragma unroll
                for (int u = 0; u < 4; ++u)
                    wgt[kw][u] = w_off[(((r * 3 + kw) * 64) + c4 * 4 + u) * NCH + tid];
#pragma unroll
            for (int col = 0; col < 10; ++col) {
                float4 qv = *(const float4*)&qs[r][col][(g << 6) + c4 * 4];
#pragma unroll
                for (int kw = 0; kw < 3; ++kw) {
                    int p = col - kw;
                    if (p >= 0 && p < 8)
                        acc[p] += wgt[kw][0] * qv.x + wgt[kw][1] * qv.y
                                + wgt[kw][2] * qv.z + wgt[kw][3] * qv.w;
                }
            }
        }
    }

#pragma unroll
    for (int p = 0; p < 8; ++p) {
        float v = acc[p];
        float s1 = v, s2 = v * v;
#pragma unroll
        for (int off = 32; off > 0; off >>= 1) {
            s1 += __shfl_xor(s1, off);
            s2 += __shfl_xor(s2, off);
        }
        if (lane == 0) { red[g][p][0] = s1; red[g][p][1] = s2; }
    }
    __syncthreads();

    const float gain = ln_g[tid];
    const float beta = ln_b[tid];
    const float wp0 = w_offp[lane * 2 + 0];
    const float wp1 = w_offp[lane * 2 + 1];

#pragma unroll
    for (int p = 0; p < 8; ++p) {
        float s1 = 0.f, s2 = 0.f;
#pragma unroll
        for (int w2 = 0; w2 < 6; ++w2) { s1 += red[w2][p][0]; s2 += red[w2][p][1]; }
        float mu  = s1 * (1.f / 384.f);
        float var = s2 * (1.f / 384.f) - mu * mu;
        float rs2 = rsqrtf(var + 1e-3f);
        float on = (acc[p] - mu) * rs2 * gain + beta;
        float t = 0.7978845608028654f * (on + 0.044715f * on * on * on);
        float ge = on * 0.5f * (1.f + tanhf(t));

        float t0 = ge * wp0, t1 = ge * wp1;
#pragma unroll
        for (int off = 32; off > 0; off >>= 1) {
            t0 += __shfl_xor(t0, off);
            t1 += __shfl_xor(t1, off);
        }
        if (lane == 0) {
            int jj = j0 + p;
            float o0 = tanhf(t0) * 16.f + (float)jj;   // pos.x
            float o1 = tanhf(t1) * 16.f + (float)i;    // pos.y
            int kidx = ((b * NGG + g) * HWN) + i * WW + jj;
            pos_out[kidx * 2]     = o0; pos_out[kidx * 2 + 1] = o1;
            ref_out[kidx * 2]     = (float)jj; ref_out[kidx * 2 + 1] = (float)i;
            // per-key bilinear precompute: col axis <- -pos.y, row axis <- -pos.x
            float mp1 = -o1, mp0 = -o0;
            float fx = floorf(mp1), fy = floorf(mp0);
            float wx = mp1 - fx, wy = mp0 - fy;
            float4 w4;
            w4.x = (1.f - wx) * (1.f - wy);
            w4.y = wx * (1.f - wy);
            w4.z = (1.f - wx) * wy;
            w4.w = wx * wy;
            kw4[kidx] = w4;
            kbase[kidx] = ((int)fx & 0xFFFF) | ((int)fy << 16);
        }
    }
}

// ---------------------------------------------------------------------------
// K3: MFMA flash attention, 4-way key-split.
// Block = 4 waves x same 16 queries; wave w owns keys [256w, 256w+256).
// Per-key bilinear weights/bases staged in LDS; zero-pad-2 RPE table ->
// maskless clamp gather with immediate-offset corner reads. LDS combine.
// ---------------------------------------------------------------------------
__global__ __launch_bounds__(256) void attn_mfma(
    const unsigned short* __restrict__ Qb, const unsigned short* __restrict__ Kb,
    const unsigned short* __restrict__ Vt, const float4* __restrict__ kw4,
    const int* __restrict__ kbase, const float* __restrict__ rpad,
    unsigned short* __restrict__ o_bf)
{
    const int bh = blockIdx.y;
    const int b = bh / NHH;
    const int h = bh - b * NHH;
    const int tid = threadIdx.x;
    const int wid = tid >> 6;          // key-chunk 0..3
    const int lane = tid & 63;
    const int g = lane >> 4;
    const int l15 = lane & 15;
    const int q = blockIdx.x * 16 + l15;

    __shared__ float rsT[67 * 68];
    __shared__ float4 kw4s[HWN];
    __shared__ int kbs[HWN];
    __shared__ unsigned short P_lds[4][16][40];
    __shared__ float obuf[4][16][34];
    __shared__ float mlbuf[4][2][16];

    {   // stage padded RPE slice (coalesced float4)
        const float4* rp = (const float4*)(rpad + h * (67 * 68));
        float4* rd = (float4*)rsT;
        for (int idx = tid; idx < (67 * 68) / 4; idx += 256) rd[idx] = rp[idx];
        // stage per-key precompute for this (b, g6)
        const float4* kwg = kw4 + (b * NGG + (h >> 1)) * HWN;
        for (int idx = tid; idx < HWN; idx += 256) kw4s[idx] = kwg[idx];
        const int* kbg = kbase + (b * NGG + (h >> 1)) * HWN;
        for (int idx = tid; idx < HWN; idx += 256) kbs[idx] = kbg[idx];
    }

    short8 qf = *(const short8*)(Qb + ((bh * HWN) + q) * DHH + g * 8);
    const int qi = q >> 5;
    const int qj = q & 31;

    const unsigned short* kbg = Kb + (bh * HWN) * DHH;
    const unsigned short* vbase = Vt + (bh * DHH) * HWN;

    f32x4 oacc[2] = {};
    float m = -1e30f, lp = 0.f;
    const f32x4 z4 = {0.f, 0.f, 0.f, 0.f};

    __syncthreads();

#pragma unroll 1
    for (int c = 0; c < 8; ++c) {
        const int kc0 = wid * 256 + c * 32;
        f32x4 st[2];
#pragma unroll
        for (int t = 0; t < 2; ++t) {
            short8 kf = *(const short8*)(kbg + (kc0 + t * 16 + l15) * DHH + g * 8);
            st[t] = __builtin_amdgcn_mfma_f32_16x16x32_bf16(kf, qf, z4, 0, 0, 0);
        }
#pragma unroll
        for (int t = 0; t < 2; ++t) {
#pragma unroll
            for (int r = 0; r < 4; ++r) {
                int k = kc0 + t * 16 + g * 4 + r;
                float4 w4 = kw4s[k];
                int bp = kbs[k];
                int ix = qi + ((bp << 16) >> 16);
                int iy = qj + (bp >> 16);
                int cx = min(max(ix, -2), 63) + 2;
                int cy = min(max(iy, -2), 63) + 2;
                int a = cy * 68 + cx;
                st[t][r] += w4.x * rsT[a] + w4.y * rsT[a + 1]
                          + w4.z * rsT[a + 68] + w4.w * rsT[a + 69];
            }
        }
        float cm = fmaxf(fmaxf(fmaxf(st[0][0], st[0][1]), fmaxf(st[0][2], st[0][3])),
                         fmaxf(fmaxf(st[1][0], st[1][1]), fmaxf(st[1][2], st[1][3])));
        cm = fmaxf(cm, __shfl_xor(cm, 16));
        cm = fmaxf(cm, __shfl_xor(cm, 32));
        if (cm > m + 8.f) {
            float scl = __expf(m - cm);
            m = cm;
            lp *= scl;
            oacc[0] *= scl;
            oacc[1] *= scl;
        }
#pragma unroll
        for (int t = 0; t < 2; ++t) {
            float p0 = __expf(st[t][0] - m);
            float p1 = __expf(st[t][1] - m);
            float p2 = __expf(st[t][2] - m);
            float p3 = __expf(st[t][3] - m);
            lp += (p0 + p1) + (p2 + p3);
            uint2 pk;
            pk.x = (unsigned)f2bf(p0) | ((unsigned)f2bf(p1) << 16);
            pk.y = (unsigned)f2bf(p2) | ((unsigned)f2bf(p3) << 16);
            *(uint2*)&P_lds[wid][l15][t * 16 + g * 4] = pk;
        }
        short8 pf = *(const short8*)&P_lds[wid][l15][g * 8];
#pragma unroll
        for (int dt = 0; dt < 2; ++dt) {
            short8 vf = *(const short8*)(vbase + (dt * 16 + l15) * HWN + kc0 + g * 8);
            oacc[dt] = __builtin_amdgcn_mfma_f32_16x16x32_bf16(vf, pf, oacc[dt], 0, 0, 0);
        }
    }

    lp += __shfl_xor(lp, 16);
    lp += __shfl_xor(lp, 32);
    if (g == 0) {
        mlbuf[wid][0][l15] = m;
        mlbuf[wid][1][l15] = lp;
    }
#pragma unroll
    for (int dt = 0; dt < 2; ++dt)
#pragma unroll
        for (int r = 0; r < 4; ++r)
            obuf[wid][l15][dt * 16 + g * 4 + r] = oacc[dt][r];
    __syncthreads();

    // combine 4 key-partials: thread = (q16 = tid>>4, d-pair = (tid&15)*2)
    const int q16 = tid >> 4;
    const int dp = (tid & 15) * 2;
    float m0 = mlbuf[0][0][q16], m1 = mlbuf[1][0][q16];
    float m2 = mlbuf[2][0][q16], m3 = mlbuf[3][0][q16];
    float mstar = fmaxf(fmaxf(m0, m1), fmaxf(m2, m3));
    float w0 = __expf(m0 - mstar), w1 = __expf(m1 - mstar);
    float w2 = __expf(m2 - mstar), w3 = __expf(m3 - mstar);
    float lsum = w0 * mlbuf[0][1][q16] + w1 * mlbuf[1][1][q16]
               + w2 * mlbuf[2][1][q16] + w3 * mlbuf[3][1][q16];
    float inv = 1.f / lsum;
    unsigned out2 = 0;
#pragma unroll
    for (int u = 0; u < 2; ++u) {
        int d = dp + u;
        float o = w0 * obuf[0][q16][d] + w1 * obuf[1][q16][d]
                + w2 * obuf[2][q16][d] + w3 * obuf[3][q16][d];
        unsigned short s = f2bf(o * inv);
        out2 |= ((unsigned)s) << (u * 16);
    }
    int qn2 = blockIdx.x * 16 + q16;
    *(unsigned*)&o_bf[((b * HWN) + qn2) * NCH + h * DHH + dp] = out2;
}

// ---------------------------------------------------------------------------
extern "C" void kernel_launch(void* const* d_in, const int* in_sizes, int n_in,
                              void* d_out, int out_size, void* d_ws, size_t ws_size,
                              hipStream_t stream) {
    (void)in_sizes; (void)n_in; (void)out_size; (void)ws_size;
    const float* x      = (const float*)d_in[0];
    const float* w_off  = (const float*)d_in[1];
    const float* b_off  = (const float*)d_in[2];
    const float* ln_g   = (const float*)d_in[3];
    const float* ln_b   = (const float*)d_in[4];
    const float* w_offp = (const float*)d_in[5];
    const float* wq     = (const float*)d_in[6];
    const float* bq     = (const float*)d_in[7];
    const float* wk     = (const float*)d_in[8];
    const float* bk     = (const float*)d_in[9];
    const float* wv     = (const float*)d_in[10];
    const float* bv     = (const float*)d_in[11];
    const float* wo     = (const float*)d_in[12];
    const float* bo     = (const float*)d_in[13];
    const float* rpe    = (const float*)d_in[14];

    float* out     = (float*)d_out;
    float* y_out   = out;             // 786432
    float* pos_out = out + 786432;    // 24576
    float* ref_out = out + 811008;    // 24576

    float* ws = (float*)d_ws;
    unsigned short* Qb   = (unsigned short*)(ws);            // 786432 bf16
    unsigned short* Kb   = (unsigned short*)(ws + 393216);   // 786432 bf16
    unsigned short* Vt   = (unsigned short*)(ws + 786432);   // 786432 bf16
    unsigned short* o_bf = (unsigned short*)(ws + 1179648);  // 786432 bf16
    float*  rpad  = ws + 1376256;                            // 54672 f32
    float4* kw4   = (float4*)(ws + 1430928);                 // 12288 float4
    int*    kbase = (int*)(ws + 1480080);                    // 12288 int
    // total ~1492368 floats ~ 5.97 MB

    // K0: padded head-major RPE table (independent of everything else)
    rpe_pad_kernel<<<dim3(214), 256, 0, stream>>>(rpe, rpad);

    // K1: q/k/v projections -> bf16 Qb (scaled), Kb, Vt (transposed)
    gemm_mfma<<<dim3(32, 6, 3), 256, 0, stream>>>(
        x, nullptr, wq, wk, wv, bq, bk, bv, nullptr, Qb, Kb, Vt, 1);

    // K2: grouped conv + LN + GELU + offset -> pos/ref + per-key precompute
    conv_offset_kernel<<<dim3(4, 32, 2), 384, 0, stream>>>(
        Qb, w_off, b_off, ln_g, ln_b, w_offp, pos_out, ref_out, kw4, kbase);

    // K3: MFMA flash attention, 4-way key-split
    attn_mfma<<<dim3(64, 24), 256, 0, stream>>>(
        Qb, Kb, Vt, kw4, kbase, rpad, o_bf);

    // K4: output projection -> y (A = bf16 o_bf)
    gemm_mfma<<<dim3(32, 6, 1), 256, 0, stream>>>(
        nullptr, o_bf, wo, wo, wo, bo, bo, bo, y_out, nullptr, nullptr, nullptr, 0);
}

// Round 5
// 91.738 us; speedup vs baseline: 4.5542x; 1.3197x over previous
//
#include <hip/hip_runtime.h>
#include <cmath>

#define HH 32
#define WW 32
#define HWN 1024
#define NCH 384
#define NHH 12
#define DHH 32
#define NGG 6

typedef __attribute__((ext_vector_type(8))) short short8;
typedef __attribute__((ext_vector_type(4))) float f32x4;

static constexpr float SCALE_QK = 0.17677669529663689f;     // 32^-0.5
static constexpr float INV_SCALE_QK = 5.656854249492381f;   // 32^0.5

__device__ inline unsigned short f2bf(float f) {
    union { float f; unsigned u; } v; v.f = f;
    return (unsigned short)((v.u + 0x7FFFu + ((v.u >> 16) & 1u)) >> 16);  // RNE
}

// ---------------------------------------------------------------------------
// K0 prep: (a) zero-padded head-major RPE table rpad[12][67][68];
//          (b) transposed bf16 conv weights Wg[n_glob=384][k=576],
//              k = (kh*3+kw)*64 + cin, value = w_off[k*384 + n_glob].
// ---------------------------------------------------------------------------
#define RPAD_N (12 * 67 * 68)
#define WG_N   (384 * 576)
__global__ __launch_bounds__(256) void prep_kernel(
    const float* __restrict__ rpe, const float* __restrict__ w_off,
    float* __restrict__ rpad, unsigned short* __restrict__ Wg)
{
    int idx = blockIdx.x * 256 + threadIdx.x;
    if (idx < RPAD_N) {
        int h = idx / (67 * 68);
        int rem = idx - h * (67 * 68);
        int row = rem / 68, col = rem - row * 68;
        int r = row - 2, c = col - 2;
        float v = 0.f;
        if (r >= 0 && r < 63 && c >= 0 && c < 63)
            v = rpe[(r * 63 + c) * NHH + h];
        rpad[idx] = v;
    } else if (idx < RPAD_N + WG_N) {
        int w = idx - RPAD_N;
        int n = w / 576, k = w - n * 576;
        Wg[n * 576 + k] = f2bf(w_off[k * NCH + n]);
    }
}

// ---------------------------------------------------------------------------
// MFMA GEMM. kmode=1: A=f32 x, z selects -> Qg bf16 group-major (*SCALE_QK) /
// Kb bf16 [bh][k][d] / Vt bf16 [bh][d][k]. kmode=0: A=bf16 o_bf, fp32 C+bias.
// ---------------------------------------------------------------------------
__global__ __launch_bounds__(256) void gemm_mfma(
    const float* __restrict__ A, const unsigned short* __restrict__ Abf,
    const float* __restrict__ W0, const float* __restrict__ W1, const float* __restrict__ W2,
    const float* __restrict__ b0, const float* __restrict__ b1, const float* __restrict__ b2,
    float* __restrict__ Cf,
    unsigned short* __restrict__ Qg, unsigned short* __restrict__ Kb,
    unsigned short* __restrict__ Vt, int kmode)
{
    const int z = blockIdx.z;
    const float* Wm = (z == 0) ? W0 : (z == 1) ? W1 : W2;
    const float* bm = (z == 0) ? b0 : (z == 1) ? b1 : b2;
    const int lane = threadIdx.x & 63;
    const int wid  = threadIdx.x >> 6;
    const int g    = lane >> 4;
    const int l15  = lane & 15;
    const int m0w  = blockIdx.x * 64 + (wid >> 1) * 32;
    const int n0w  = blockIdx.y * 64 + (wid & 1) * 32;

    f32x4 acc[2][2] = {};

#pragma unroll 2
    for (int k0 = 0; k0 < NCH; k0 += 32) {
        short8 af[2];
#pragma unroll
        for (int i = 0; i < 2; ++i) {
            if (kmode == 0) {
                af[i] = *(const short8*)(Abf + (m0w + i * 16 + l15) * NCH + k0 + g * 8);
            } else {
                const float* ap = A + (m0w + i * 16 + l15) * NCH + k0 + g * 8;
                float4 a0 = *(const float4*)ap;
                float4 a1 = *(const float4*)(ap + 4);
                short8 t;
                t[0] = (short)f2bf(a0.x); t[1] = (short)f2bf(a0.y);
                t[2] = (short)f2bf(a0.z); t[3] = (short)f2bf(a0.w);
                t[4] = (short)f2bf(a1.x); t[5] = (short)f2bf(a1.y);
                t[6] = (short)f2bf(a1.z); t[7] = (short)f2bf(a1.w);
                af[i] = t;
            }
        }
        short8 bfr[2];
#pragma unroll
        for (int j = 0; j < 2; ++j) {
            const float* wp = Wm + (k0 + g * 8) * NCH + n0w + j * 16 + l15;
            short8 t;
#pragma unroll
            for (int u = 0; u < 8; ++u) t[u] = (short)f2bf(wp[u * NCH]);
            bfr[j] = t;
        }
#pragma unroll
        for (int i = 0; i < 2; ++i)
#pragma unroll
            for (int j = 0; j < 2; ++j)
                acc[i][j] = __builtin_amdgcn_mfma_f32_16x16x32_bf16(
                    af[i], bfr[j], acc[i][j], 0, 0, 0);
    }

    if (kmode == 0) {
#pragma unroll
        for (int i = 0; i < 2; ++i)
#pragma unroll
            for (int j = 0; j < 2; ++j) {
                int col = n0w + j * 16 + l15;
                float bias = bm[col];
#pragma unroll
                for (int r = 0; r < 4; ++r) {
                    int row = m0w + i * 16 + g * 4 + r;
                    Cf[row * NCH + col] = acc[i][j][r] + bias;
                }
            }
    } else if (z == 2) {
#pragma unroll
        for (int i = 0; i < 2; ++i) {
            int krow = m0w + i * 16 + g * 4;
            int b_ = krow >> 10, kk = krow & 1023;
#pragma unroll
            for (int j = 0; j < 2; ++j) {
                int col = n0w + j * 16 + l15;
                int h = col >> 5, d = col & 31;
                float bias = bm[col];
                unsigned short s0 = f2bf(acc[i][j][0] + bias);
                unsigned short s1 = f2bf(acc[i][j][1] + bias);
                unsigned short s2 = f2bf(acc[i][j][2] + bias);
                unsigned short s3 = f2bf(acc[i][j][3] + bias);
                uint2 pk;
                pk.x = (unsigned)s0 | ((unsigned)s1 << 16);
                pk.y = (unsigned)s2 | ((unsigned)s3 << 16);
                *(uint2*)&Vt[(((b_ * NHH) + h) * DHH + d) * HWN + kk] = pk;
            }
        }
    } else if (z == 0) {
        // Qg group-major: [b][g6][p][c64], c = (h&1)*32 + d, scaled
#pragma unroll
        for (int i = 0; i < 2; ++i)
#pragma unroll
            for (int j = 0; j < 2; ++j) {
                int col = n0w + j * 16 + l15;
                int h = col >> 5, d = col & 31;
                float bias = bm[col];
#pragma unroll
                for (int r = 0; r < 4; ++r) {
                    int row = m0w + i * 16 + g * 4 + r;
                    int b_ = row >> 10, q = row & 1023;
                    Qg[(((b_ * NGG + (h >> 1)) * HWN + q) * 64) + (h & 1) * 32 + d] =
                        f2bf((acc[i][j][r] + bias) * SCALE_QK);
                }
            }
    } else {
#pragma unroll
        for (int i = 0; i < 2; ++i)
#pragma unroll
            for (int j = 0; j < 2; ++j) {
                int col = n0w + j * 16 + l15;
                int h = col >> 5, d = col & 31;
                float bias = bm[col];
#pragma unroll
                for (int r = 0; r < 4; ++r) {
                    int row = m0w + i * 16 + g * 4 + r;
                    int b_ = row >> 10, q = row & 1023;
                    Kb[(((b_ * NHH) + h) * HWN + q) * DHH + d] = f2bf(acc[i][j][r] + bias);
                }
            }
    }
}

// ---------------------------------------------------------------------------
// K2a: grouped 3x3 conv as shifted-window MFMA GEMM.
// Block = 1 wave, tile M32 (one image row of one (b,g)) x N64.
// A = Qg (scaled bf16), B = Wg (bf16, [n][k576]); epilogue *INV_SCALE + b_off.
// SAME padding: row validity uniform per block; col masks on 2 edge lanes.
// ---------------------------------------------------------------------------
__global__ __launch_bounds__(64) void conv_mfma(
    const unsigned short* __restrict__ Qg, const unsigned short* __restrict__ Wg,
    const float* __restrict__ b_off, float* __restrict__ conv_out)
{
    const int bg = blockIdx.y;            // 0..11 = b*6+g
    const int b = bg / NGG, g = bg - b * NGG;
    const int m0 = blockIdx.x * 32;       // pixel row tile (= image row blockIdx.x)
    const int lane = threadIdx.x;
    const int l15 = lane & 15, gk = lane >> 4;

    const unsigned short* Ab = Qg + (bg * HWN) * 64;
    const unsigned short* Bb = Wg + (g * 64) * 576;

    f32x4 acc[2][4] = {};
    const int pr0 = m0 + l15, pr1 = m0 + 16 + l15;
    const int irow = m0 >> 5;
    const int4 zz = {0, 0, 0, 0};

#pragma unroll
    for (int kh = 0; kh < 3; ++kh) {
        int ii = irow + kh - 1;
        if ((unsigned)ii >= (unsigned)HH) continue;   // uniform skip (zero rows)
#pragma unroll
        for (int kw = 0; kw < 3; ++kw) {
            int dp = (kh - 1) * 32 + (kw - 1);
            bool v0 = (unsigned)(l15 + kw - 1) < (unsigned)WW;       // j0 = l15
            bool v1 = (unsigned)(16 + l15 + kw - 1) < (unsigned)WW;  // j1 = 16+l15
            int p0 = min(max(pr0 + dp, 0), HWN - 1);
            int p1 = min(max(pr1 + dp, 0), HWN - 1);
            const int kt = (kh * 3 + kw) * 64;
#pragma unroll
            for (int cc = 0; cc < 2; ++cc) {
                int4 ra = *(const int4*)(Ab + p0 * 64 + cc * 32 + gk * 8);
                int4 rb = *(const int4*)(Ab + p1 * 64 + cc * 32 + gk * 8);
                int4 a0i = v0 ? ra : zz;
                int4 a1i = v1 ? rb : zz;
                short8 a0 = *(short8*)&a0i;
                short8 a1 = *(short8*)&a1i;
                short8 bf[4];
#pragma unroll
                for (int nj = 0; nj < 4; ++nj)
                    bf[nj] = *(const short8*)(Bb + (nj * 16 + l15) * 576 + kt + cc * 32 + gk * 8);
#pragma unroll
                for (int nj = 0; nj < 4; ++nj) {
                    acc[0][nj] = __builtin_amdgcn_mfma_f32_16x16x32_bf16(a0, bf[nj], acc[0][nj], 0, 0, 0);
                    acc[1][nj] = __builtin_amdgcn_mfma_f32_16x16x32_bf16(a1, bf[nj], acc[1][nj], 0, 0, 0);
                }
            }
        }
    }

#pragma unroll
    for (int mi = 0; mi < 2; ++mi)
#pragma unroll
        for (int nj = 0; nj < 4; ++nj) {
            int ch = g * 64 + nj * 16 + l15;
            float bias = b_off[ch];
#pragma unroll
            for (int r = 0; r < 4; ++r) {
                int prow = m0 + mi * 16 + gk * 4 + r;
                conv_out[((b * HWN) + prow) * NCH + ch] = acc[mi][nj][r] * INV_SCALE_QK + bias;
            }
        }
}

// ---------------------------------------------------------------------------
// K2b: per-pixel LN -> GELU -> per-group offset proj -> pos/ref + per-key
// bilinear precompute. 1 pixel per block, thread = channel, wave = group.
// ---------------------------------------------------------------------------
__global__ __launch_bounds__(384) void ln_offset_kernel(
    const float* __restrict__ co, const float* __restrict__ ln_g,
    const float* __restrict__ ln_b, const float* __restrict__ w_offp,
    float* __restrict__ pos_out, float* __restrict__ ref_out,
    float4* __restrict__ kw4, int* __restrict__ kbase)
{
    const int pg = blockIdx.x;            // 0..2047
    const int b = pg >> 10, p = pg & 1023;
    const int i = p >> 5, j = p & 31;
    const int tid = threadIdx.x;
    const int g = tid >> 6, lane = tid & 63;

    __shared__ float red[6][2];

    float v = co[pg * NCH + tid];
    float s1 = v, s2 = v * v;
#pragma unroll
    for (int off = 32; off > 0; off >>= 1) {
        s1 += __shfl_xor(s1, off);
        s2 += __shfl_xor(s2, off);
    }
    if (lane == 0) { red[g][0] = s1; red[g][1] = s2; }
    __syncthreads();
    float t1s = 0.f, t2s = 0.f;
#pragma unroll
    for (int w = 0; w < 6; ++w) { t1s += red[w][0]; t2s += red[w][1]; }
    float mu  = t1s * (1.f / 384.f);
    float var = t2s * (1.f / 384.f) - mu * mu;
    float rs2 = rsqrtf(var + 1e-3f);
    float on = (v - mu) * rs2 * ln_g[tid] + ln_b[tid];
    float t = 0.7978845608028654f * (on + 0.044715f * on * on * on);
    float ge = on * 0.5f * (1.f + tanhf(t));

    float t0 = ge * w_offp[lane * 2 + 0];
    float t1 = ge * w_offp[lane * 2 + 1];
#pragma unroll
    for (int off = 32; off > 0; off >>= 1) {
        t0 += __shfl_xor(t0, off);
        t1 += __shfl_xor(t1, off);
    }
    if (lane == 0) {
        float o0 = tanhf(t0) * 16.f + (float)j;   // pos.x
        float o1 = tanhf(t1) * 16.f + (float)i;   // pos.y
        int kidx = (b * NGG + g) * HWN + p;
        pos_out[kidx * 2]     = o0; pos_out[kidx * 2 + 1] = o1;
        ref_out[kidx * 2]     = (float)j; ref_out[kidx * 2 + 1] = (float)i;
        float mp1 = -o1, mp0 = -o0;
        float fx = floorf(mp1), fy = floorf(mp0);
        float wx = mp1 - fx, wy = mp0 - fy;
        float4 w4;
        w4.x = (1.f - wx) * (1.f - wy);
        w4.y = wx * (1.f - wy);
        w4.z = (1.f - wx) * wy;
        w4.w = wx * wy;
        kw4[kidx] = w4;
        kbase[kidx] = ((int)fx & 0xFFFF) | ((int)fy << 16);
    }
}

// ---------------------------------------------------------------------------
// K3: MFMA flash attention, 4-way key-split (unchanged from R3 except Q layout).
// ---------------------------------------------------------------------------
__global__ __launch_bounds__(256) void attn_mfma(
    const unsigned short* __restrict__ Qg, const unsigned short* __restrict__ Kb,
    const unsigned short* __restrict__ Vt, const float4* __restrict__ kw4,
    const int* __restrict__ kbase, const float* __restrict__ rpad,
    unsigned short* __restrict__ o_bf)
{
    const int bh = blockIdx.y;
    const int b = bh / NHH;
    const int h = bh - b * NHH;
    const int tid = threadIdx.x;
    const int wid = tid >> 6;
    const int lane = tid & 63;
    const int g = lane >> 4;
    const int l15 = lane & 15;
    const int q = blockIdx.x * 16 + l15;

    __shared__ float rsT[67 * 68];
    __shared__ float4 kw4s[HWN];
    __shared__ int kbs[HWN];
    __shared__ unsigned short P_lds[4][16][40];
    __shared__ float obuf[4][16][34];
    __shared__ float mlbuf[4][2][16];

    {
        const float4* rp = (const float4*)(rpad + h * (67 * 68));
        float4* rd = (float4*)rsT;
        for (int idx = tid; idx < (67 * 68) / 4; idx += 256) rd[idx] = rp[idx];
        const float4* kwg = kw4 + (b * NGG + (h >> 1)) * HWN;
        for (int idx = tid; idx < HWN; idx += 256) kw4s[idx] = kwg[idx];
        const int* kbg2 = kbase + (b * NGG + (h >> 1)) * HWN;
        for (int idx = tid; idx < HWN; idx += 256) kbs[idx] = kbg2[idx];
    }

    short8 qf = *(const short8*)(Qg + ((b * NGG + (h >> 1)) * HWN + q) * 64 + (h & 1) * 32 + g * 8);
    const int qi = q >> 5;
    const int qj = q & 31;

    const unsigned short* kbg = Kb + (bh * HWN) * DHH;
    const unsigned short* vbase = Vt + (bh * DHH) * HWN;

    f32x4 oacc[2] = {};
    float m = -1e30f, lp = 0.f;
    const f32x4 z4 = {0.f, 0.f, 0.f, 0.f};

    __syncthreads();

#pragma unroll 1
    for (int c = 0; c < 8; ++c) {
        const int kc0 = wid * 256 + c * 32;
        f32x4 st[2];
#pragma unroll
        for (int t = 0; t < 2; ++t) {
            short8 kf = *(const short8*)(kbg + (kc0 + t * 16 + l15) * DHH + g * 8);
            st[t] = __builtin_amdgcn_mfma_f32_16x16x32_bf16(kf, qf, z4, 0, 0, 0);
        }
#pragma unroll
        for (int t = 0; t < 2; ++t) {
#pragma unroll
            for (int r = 0; r < 4; ++r) {
                int k = kc0 + t * 16 + g * 4 + r;
                float4 w4 = kw4s[k];
                int bp = kbs[k];
                int ix = qi + ((bp << 16) >> 16);
                int iy = qj + (bp >> 16);
                int cx = min(max(ix, -2), 63) + 2;
                int cy = min(max(iy, -2), 63) + 2;
                int a = cy * 68 + cx;
                st[t][r] += w4.x * rsT[a] + w4.y * rsT[a + 1]
                          + w4.z * rsT[a + 68] + w4.w * rsT[a + 69];
            }
        }
        float cm = fmaxf(fmaxf(fmaxf(st[0][0], st[0][1]), fmaxf(st[0][2], st[0][3])),
                         fmaxf(fmaxf(st[1][0], st[1][1]), fmaxf(st[1][2], st[1][3])));
        cm = fmaxf(cm, __shfl_xor(cm, 16));
        cm = fmaxf(cm, __shfl_xor(cm, 32));
        if (cm > m + 8.f) {
            float scl = __expf(m - cm);
            m = cm;
            lp *= scl;
            oacc[0] *= scl;
            oacc[1] *= scl;
        }
#pragma unroll
        for (int t = 0; t < 2; ++t) {
            float p0 = __expf(st[t][0] - m);
            float p1 = __expf(st[t][1] - m);
            float p2 = __expf(st[t][2] - m);
            float p3 = __expf(st[t][3] - m);
            lp += (p0 + p1) + (p2 + p3);
            uint2 pk;
            pk.x = (unsigned)f2bf(p0) | ((unsigned)f2bf(p1) << 16);
            pk.y = (unsigned)f2bf(p2) | ((unsigned)f2bf(p3) << 16);
            *(uint2*)&P_lds[wid][l15][t * 16 + g * 4] = pk;
        }
        short8 pf = *(const short8*)&P_lds[wid][l15][g * 8];
#pragma unroll
        for (int dt = 0; dt < 2; ++dt) {
            short8 vf = *(const short8*)(vbase + (dt * 16 + l15) * HWN + kc0 + g * 8);
            oacc[dt] = __builtin_amdgcn_mfma_f32_16x16x32_bf16(vf, pf, oacc[dt], 0, 0, 0);
        }
    }

    lp += __shfl_xor(lp, 16);
    lp += __shfl_xor(lp, 32);
    if (g == 0) {
        mlbuf[wid][0][l15] = m;
        mlbuf[wid][1][l15] = lp;
    }
#pragma unroll
    for (int dt = 0; dt < 2; ++dt)
#pragma unroll
        for (int r = 0; r < 4; ++r)
            obuf[wid][l15][dt * 16 + g * 4 + r] = oacc[dt][r];
    __syncthreads();

    const int q16 = tid >> 4;
    const int dp = (tid & 15) * 2;
    float m0 = mlbuf[0][0][q16], m1 = mlbuf[1][0][q16];
    float m2 = mlbuf[2][0][q16], m3 = mlbuf[3][0][q16];
    float mstar = fmaxf(fmaxf(m0, m1), fmaxf(m2, m3));
    float w0 = __expf(m0 - mstar), w1 = __expf(m1 - mstar);
    float w2 = __expf(m2 - mstar), w3 = __expf(m3 - mstar);
    float lsum = w0 * mlbuf[0][1][q16] + w1 * mlbuf[1][1][q16]
               + w2 * mlbuf[2][1][q16] + w3 * mlbuf[3][1][q16];
    float inv = 1.f / lsum;
    unsigned out2 = 0;
#pragma unroll
    for (int u = 0; u < 2; ++u) {
        int d = dp + u;
        float o = w0 * obuf[0][q16][d] + w1 * obuf[1][q16][d]
                + w2 * obuf[2][q16][d] + w3 * obuf[3][q16][d];
        unsigned short s = f2bf(o * inv);
        out2 |= ((unsigned)s) << (u * 16);
    }
    int qn2 = blockIdx.x * 16 + q16;
    *(unsigned*)&o_bf[((b * HWN) + qn2) * NCH + h * DHH + dp] = out2;
}

// ---------------------------------------------------------------------------
extern "C" void kernel_launch(void* const* d_in, const int* in_sizes, int n_in,
                              void* d_out, int out_size, void* d_ws, size_t ws_size,
                              hipStream_t stream) {
    (void)in_sizes; (void)n_in; (void)out_size; (void)ws_size;
    const float* x      = (const float*)d_in[0];
    const float* w_off  = (const float*)d_in[1];
    const float* b_off  = (const float*)d_in[2];
    const float* ln_g   = (const float*)d_in[3];
    const float* ln_b   = (const float*)d_in[4];
    const float* w_offp = (const float*)d_in[5];
    const float* wq     = (const float*)d_in[6];
    const float* bq     = (const float*)d_in[7];
    const float* wk     = (const float*)d_in[8];
    const float* bk     = (const float*)d_in[9];
    const float* wv     = (const float*)d_in[10];
    const float* bv     = (const float*)d_in[11];
    const float* wo     = (const float*)d_in[12];
    const float* bo     = (const float*)d_in[13];
    const float* rpe    = (const float*)d_in[14];

    float* out     = (float*)d_out;
    float* y_out   = out;             // 786432
    float* pos_out = out + 786432;    // 24576
    float* ref_out = out + 811008;    // 24576

    float* ws = (float*)d_ws;
    unsigned short* Qg   = (unsigned short*)(ws);            // 786432 bf16
    unsigned short* Kb   = (unsigned short*)(ws + 393216);   // 786432 bf16
    unsigned short* Vt   = (unsigned short*)(ws + 786432);   // 786432 bf16
    unsigned short* o_bf = (unsigned short*)(ws + 1179648);  // 786432 bf16
    float*  rpad  = ws + 1376256;                            // 54672 f32
    float4* kw4   = (float4*)(ws + 1430928);                 // 12288 float4
    int*    kbase = (int*)(ws + 1480080);                    // 12288 int
    unsigned short* Wg = (unsigned short*)(ws + 1492368);    // 221184 bf16
    float* conv_ws = ws + 1602960;                           // 786432 f32
    // total ~2389392 floats ~ 9.56 MB

    // K0: padded RPE table + bf16 transposed conv weights
    prep_kernel<<<dim3((RPAD_N + WG_N + 255) / 256), 256, 0, stream>>>(
        rpe, w_off, rpad, Wg);

    // K1: q/k/v projections -> Qg (group-major, scaled), Kb, Vt
    gemm_mfma<<<dim3(32, 6, 3), 256, 0, stream>>>(
        x, nullptr, wq, wk, wv, bq, bk, bv, nullptr, Qg, Kb, Vt, 1);

    // K2a: grouped conv via shifted-window MFMA
    conv_mfma<<<dim3(32, 12), 64, 0, stream>>>(Qg, Wg, b_off, conv_ws);

    // K2b: LN + GELU + offset proj -> pos/ref + per-key precompute
    ln_offset_kernel<<<dim3(2048), 384, 0, stream>>>(
        conv_ws, ln_g, ln_b, w_offp, pos_out, ref_out, kw4, kbase);

    // K3: MFMA flash attention
    attn_mfma<<<dim3(64, 24), 256, 0, stream>>>(
        Qg, Kb, Vt, kw4, kbase, rpad, o_bf);

    // K4: output projection -> y
    gemm_mfma<<<dim3(32, 6, 1), 256, 0, stream>>>(
        nullptr, o_bf, wo, wo, wo, bo, bo, bo, y_out, nullptr, nullptr, nullptr, 0);
}